// Round 2
// baseline (441.848 us; speedup 1.0000x reference)
//
#include <hip/hip_runtime.h>

// SQDDPG mixer, MI355X. Round 2: fix threefry word selection
// (partitionable mode returns bits1 ^ bits2 for 32-bit draws).
//
// Dims (fixed by the reference):
//   bs=32, t=32 -> B=1024; A=8 agents, NA=16 actions, S=16 samples,
//   SD=256 state dim, EMB=256, IN_DIM=384.
//
// Algebra:
//   sW[b,:]  = st[b] @ W1[0:256,:] + b1            (prep kernel)
//   v[b]     = relu(st[b]@Vw1+Vb1) @ Vw2 + Vb2     (prep kernel)
//   c[j,:]   = sum_na qs[b, rank(j), na] * W1[256+j*16+na, :]
//   h1[m,:]  = relu(sW + sum_{j<=m} c[j])          (running prefix, m=0..7)
//   h2       = relu(h1 @ W2 + b2); adv[m] = h2[m,:].W3
//   out[b,i] = v[b] + b3 + mean_s adv[s, pos[s,i]]   (pos[i] = agent w/ rank i)

#define A_N   8
#define NA_N  16
#define S_N   16
#define SD    256
#define EMB   256
#define B_TOT 1024
#define H1S   20   // padded LDS stride for h1t[k][m]: 80B row, 16B-aligned

// ---------------------------------------------------------------------------
// JAX threefry2x32, key = jax.random.key(42) -> (0, 42).
// ---------------------------------------------------------------------------
__device__ __forceinline__ void tf2x32(unsigned c0, unsigned c1,
                                       unsigned& o0, unsigned& o1) {
  const unsigned ks0 = 0u;
  const unsigned ks1 = 42u;
  const unsigned ks2 = 0x1BD11BDAu ^ 42u;
  unsigned x0 = c0 + ks0;
  unsigned x1 = c1 + ks1;
#define TF_RND(r) { x0 += x1; x1 = (x1 << (r)) | (x1 >> (32 - (r))); x1 ^= x0; }
  TF_RND(13) TF_RND(15) TF_RND(26) TF_RND(6)  x0 += ks1; x1 += ks2 + 1u;
  TF_RND(17) TF_RND(29) TF_RND(16) TF_RND(24) x0 += ks2; x1 += ks0 + 2u;
  TF_RND(13) TF_RND(15) TF_RND(26) TF_RND(6)  x0 += ks0; x1 += ks1 + 3u;
  TF_RND(17) TF_RND(29) TF_RND(16) TF_RND(24) x0 += ks1; x1 += ks2 + 4u;
  TF_RND(13) TF_RND(15) TF_RND(26) TF_RND(6)  x0 += ks2; x1 += ks0 + 5u;
#undef TF_RND
  o0 = x0; o1 = x1;
}

// RNG_VARIANT: 0 = partitionable mode (JAX >= 0.4.30 default): per-element
//                  64-bit counter (hi=0, lo=idx), bits = o0 ^ o1 (XOR of the
//                  two threefry output words -- per jax/_src/prng.py).
//              1 = partitionable, HIGH word only (o0).
//              2 = original (non-partitionable) mode: pairs (i, i+65536),
//                  first half takes o0, second half o1.
//              3 = partitionable, LOW word only (o1). [tried R1: FAILED 0.14]
#define RNG_VARIANT 0

__device__ __forceinline__ float jax_uniform(unsigned idx) {
  unsigned o0, o1, bits;
#if RNG_VARIANT == 0
  tf2x32(0u, idx, o0, o1);
  bits = o0 ^ o1;
#elif RNG_VARIANT == 1
  tf2x32(0u, idx, o0, o1);
  bits = o0;
#elif RNG_VARIANT == 2
  const unsigned HALF = 65536u;  // total elements 131072
  if (idx < HALF) { tf2x32(idx, idx + HALF, o0, o1); bits = o0; }
  else            { tf2x32(idx - HALF, idx, o0, o1); bits = o1; }
#else
  tf2x32(0u, idx, o0, o1);
  bits = o1;
#endif
  return __uint_as_float((bits >> 9) | 0x3F800000u) - 1.0f;
}

// ---------------------------------------------------------------------------
// Prep: per-b state projections.  grid = 1024 blocks (one per b), 256 thr.
// ---------------------------------------------------------------------------
__global__ __launch_bounds__(256) void prep_kernel(
    const float* __restrict__ states, const float* __restrict__ W1,
    const float* __restrict__ b1, const float* __restrict__ Vw1,
    const float* __restrict__ Vb1, const float* __restrict__ Vw2,
    const float* __restrict__ Vb2, float* __restrict__ sW,
    float* __restrict__ vout) {
  __shared__ float st_l[SD];
  __shared__ float red_l[4];
  const int b = blockIdx.x;
  const int n = threadIdx.x;

  st_l[n] = states[b * SD + n];
  __syncthreads();

  float accS = b1[n];
  float accV = Vb1[n];
#pragma unroll 8
  for (int k = 0; k < SD; ++k) {
    const float s = st_l[k];
    accS = fmaf(s, W1[k * EMB + n], accS);   // W1 top block rows 0..255
    accV = fmaf(s, Vw1[k * EMB + n], accV);
  }
  sW[b * EMB + n] = accS;

  float contrib = fmaxf(accV, 0.f) * Vw2[n];
#pragma unroll
  for (int off = 32; off; off >>= 1) contrib += __shfl_down(contrib, off);
  if ((n & 63) == 0) red_l[n >> 6] = contrib;
  __syncthreads();
  if (n == 0) vout[b] = red_l[0] + red_l[1] + red_l[2] + red_l[3] + Vb2[0];
}

// ---------------------------------------------------------------------------
// Main: one block per b, 256 threads; s processed in pairs.
// ---------------------------------------------------------------------------
__global__ __launch_bounds__(256) void main_kernel(
    const float* __restrict__ agent_qs, const float* __restrict__ W1,
    const float* __restrict__ W2, const float* __restrict__ b2,
    const float* __restrict__ W3, const float* __restrict__ b3,
    const float* __restrict__ sW, const float* __restrict__ vv,
    float* __restrict__ out) {
  __shared__ float qs_l[A_N * NA_N];     // 128 floats
  __shared__ float u_l[2][A_N];
  __shared__ int   inv_l[2][A_N];        // inv[a] = stable rank of agent a
  __shared__ int   pos_l[2][A_N];        // pos[r] = agent with rank r
  __shared__ float h1t[EMB * H1S];       // transposed h1: [feature k][row m]
  __shared__ float red_l[4][16];
  __shared__ float adv_l[16];

  const int b = blockIdx.x;
  const int n = threadIdx.x;

  if (n < A_N * NA_N) qs_l[n] = agent_qs[b * (A_N * NA_N) + n];
  const float sWn = sW[b * EMB + n];
  const float b2n = b2[n];
  const float w3n = W3[n];
  const float* __restrict__ W1b = W1 + SD * EMB;  // rows 256..383

  float shacc = 0.f;  // threads 0..7: running sum over s of adv at pos[i]

  __syncthreads();

  for (int s0 = 0; s0 < S_N; s0 += 2) {
    // --- RNG for the two samples ---
    if (n < 16) {
      const int g = n >> 3, a = n & 7;
      const unsigned idx = (unsigned)((b * S_N + s0 + g) * A_N + a);
      u_l[g][a] = jax_uniform(idx);
    }
    __syncthreads();
    // --- stable ranks (argsort semantics) ---
    if (n < 16) {
      const int g = n >> 3, a = n & 7;
      const float u = u_l[g][a];
      int r = 0;
#pragma unroll
      for (int a2 = 0; a2 < A_N; ++a2) {
        const float u2 = u_l[g][a2];
        r += (u2 < u || (u2 == u && a2 < a)) ? 1 : 0;
      }
      inv_l[g][a] = r;
      pos_l[g][r] = a;
    }
    __syncthreads();

    // --- layer 1: prefix-sum trick, thread n owns column n ---
#pragma unroll
    for (int g = 0; g < 2; ++g) {
      float racc = sWn;
#pragma unroll
      for (int j = 0; j < A_N; ++j) {
        const int a = inv_l[g][j];
        const float* __restrict__ qrow = &qs_l[a * NA_N];
        const float* __restrict__ wrow = &W1b[(j * NA_N) * EMB + n];
#pragma unroll
        for (int na = 0; na < NA_N; ++na)
          racc = fmaf(qrow[na], wrow[na * EMB], racc);
        h1t[n * H1S + (g * A_N + j)] = fmaxf(racc, 0.f);
      }
    }
    __syncthreads();

    // --- layer 2: 16 rows x 256 cols, thread n owns output column n ---
    float hacc[16];
#pragma unroll
    for (int m = 0; m < 16; ++m) hacc[m] = b2n;
    const float* __restrict__ w2col = W2 + n;
#pragma unroll 4
    for (int k = 0; k < EMB; ++k) {
      const float w2 = w2col[k * EMB];
      const float4* __restrict__ hr = (const float4*)&h1t[k * H1S];
      const float4 q0 = hr[0], q1 = hr[1], q2 = hr[2], q3 = hr[3];
      hacc[0]  = fmaf(q0.x, w2, hacc[0]);
      hacc[1]  = fmaf(q0.y, w2, hacc[1]);
      hacc[2]  = fmaf(q0.z, w2, hacc[2]);
      hacc[3]  = fmaf(q0.w, w2, hacc[3]);
      hacc[4]  = fmaf(q1.x, w2, hacc[4]);
      hacc[5]  = fmaf(q1.y, w2, hacc[5]);
      hacc[6]  = fmaf(q1.z, w2, hacc[6]);
      hacc[7]  = fmaf(q1.w, w2, hacc[7]);
      hacc[8]  = fmaf(q2.x, w2, hacc[8]);
      hacc[9]  = fmaf(q2.y, w2, hacc[9]);
      hacc[10] = fmaf(q2.z, w2, hacc[10]);
      hacc[11] = fmaf(q2.w, w2, hacc[11]);
      hacc[12] = fmaf(q3.x, w2, hacc[12]);
      hacc[13] = fmaf(q3.y, w2, hacc[13]);
      hacc[14] = fmaf(q3.z, w2, hacc[14]);
      hacc[15] = fmaf(q3.w, w2, hacc[15]);
    }

    // --- layer 3: relu, W3 dot, block-reduce over columns ---
#pragma unroll
    for (int m = 0; m < 16; ++m) {
      float v = fmaxf(hacc[m], 0.f) * w3n;
#pragma unroll
      for (int off = 32; off; off >>= 1) v += __shfl_down(v, off);
      if ((n & 63) == 0) red_l[n >> 6][m] = v;
    }
    __syncthreads();
    if (n < 16) adv_l[n] = red_l[0][n] + red_l[1][n] + red_l[2][n] + red_l[3][n];
    __syncthreads();
    if (n < A_N)
      shacc += adv_l[0 * A_N + pos_l[0][n]] + adv_l[1 * A_N + pos_l[1][n]];
    __syncthreads();  // protect u_l/pos_l/h1t before next iteration
  }

  if (n < A_N)
    out[b * A_N + n] = shacc * (1.f / 16.f) + b3[0] + vv[b];
}

// ---------------------------------------------------------------------------
extern "C" void kernel_launch(void* const* d_in, const int* in_sizes, int n_in,
                              void* d_out, int out_size, void* d_ws,
                              size_t ws_size, hipStream_t stream) {
  const float* states   = (const float*)d_in[0];
  const float* agent_qs = (const float*)d_in[1];
  const float* W1       = (const float*)d_in[2];
  const float* b1       = (const float*)d_in[3];
  const float* W2       = (const float*)d_in[4];
  const float* b2       = (const float*)d_in[5];
  const float* W3       = (const float*)d_in[6];
  const float* b3       = (const float*)d_in[7];
  const float* Vw1      = (const float*)d_in[8];
  const float* Vb1      = (const float*)d_in[9];
  const float* Vw2      = (const float*)d_in[10];
  const float* Vb2      = (const float*)d_in[11];
  float* out = (float*)d_out;

  float* sW = (float*)d_ws;            // 1024*256 floats = 1 MB
  float* vv = sW + B_TOT * EMB;        // 1024 floats

  prep_kernel<<<B_TOT, 256, 0, stream>>>(states, W1, b1, Vw1, Vb1, Vw2, Vb2,
                                         sW, vv);
  main_kernel<<<B_TOT, 256, 0, stream>>>(agent_qs, W1, W2, b2, W3, b3, sW, vv,
                                         out);
}

// Round 3
// 164.726 us; speedup vs baseline: 2.6823x; 2.6823x over previous
//
#include <hip/hip_runtime.h>

// SQDDPG mixer, MI355X. Round 3: MFMA rewrite of the MLP.
//
// Validated facts from R2 (bit-exact pass): threefry partitionable mode with
// bits = o0^o1, counter (0, idx=b*128+n); stable ranks; slot j of the
// coalition vector uses qs[inv_l[j]]; output agent n reads prefix-row
// pos_l[n]. DO NOT CHANGE THESE.
//
// Structure:
//   prep_kernel  (256 blocks x 4 b): sW[b,:] = st@W1top + b1 (fp32),
//                v[b] = relu(st@Vw1+Vb1)@Vw2+Vb2 (fp32)
//   pack_kernel  : W1 bottom rows (128x256) and W2 (256x256) -> bf16 in
//                MFMA B-fragment order: elem j of slot (t,u,L) is
//                B[k=t*32+(L>>4)*8+j][n=u*16+(L&15)]
//   main_kernel  (1024 blocks): per pass (M=64 rows = 8 samples x 8 prefix):
//                X (A-frag LDS, bf16) -> MFMA layer1 (C init sW) -> relu ->
//                bf16 scatter to layer2 A-frag LDS -> MFMA layer2 (C init b2)
//                -> relu,*W3, quad shuffle-reduce -> marginals -> gather.

#define A_N   8
#define NA_N  16
#define S_N   16
#define SD    256
#define EMB   256
#define B_TOT 1024

typedef __bf16 bf16x8 __attribute__((ext_vector_type(8)));
typedef float  f32x4  __attribute__((ext_vector_type(4)));

__device__ __forceinline__ f32x4 splat4(float v) {
  f32x4 x; x[0] = v; x[1] = v; x[2] = v; x[3] = v; return x;
}
__device__ __forceinline__ bf16x8 zero8() {
  bf16x8 z;
#pragma unroll
  for (int j = 0; j < 8; ++j) z[j] = (__bf16)0.0f;
  return z;
}

// ---------------------------------------------------------------------------
// JAX threefry2x32, key = (0, 42); partitionable draw: bits = o0 ^ o1.
// ---------------------------------------------------------------------------
__device__ __forceinline__ float jax_uniform(unsigned idx) {
  const unsigned ks0 = 0u, ks1 = 42u, ks2 = 0x1BD11BDAu ^ 42u;
  unsigned x0 = 0u + ks0;
  unsigned x1 = idx + ks1;
#define TF_RND(r) { x0 += x1; x1 = (x1 << (r)) | (x1 >> (32 - (r))); x1 ^= x0; }
  TF_RND(13) TF_RND(15) TF_RND(26) TF_RND(6)  x0 += ks1; x1 += ks2 + 1u;
  TF_RND(17) TF_RND(29) TF_RND(16) TF_RND(24) x0 += ks2; x1 += ks0 + 2u;
  TF_RND(13) TF_RND(15) TF_RND(26) TF_RND(6)  x0 += ks0; x1 += ks1 + 3u;
  TF_RND(17) TF_RND(29) TF_RND(16) TF_RND(24) x0 += ks1; x1 += ks2 + 4u;
  TF_RND(13) TF_RND(15) TF_RND(26) TF_RND(6)  x0 += ks2; x1 += ks0 + 5u;
#undef TF_RND
  const unsigned bits = x0 ^ x1;
  return __uint_as_float((bits >> 9) | 0x3F800000u) - 1.0f;
}

// ---------------------------------------------------------------------------
// Prep: 256 blocks x 4 b each. Weights read once per block (L2 traffic /4).
// ---------------------------------------------------------------------------
__global__ __launch_bounds__(256) void prep_kernel(
    const float* __restrict__ states, const float* __restrict__ W1,
    const float* __restrict__ b1, const float* __restrict__ Vw1,
    const float* __restrict__ Vb1, const float* __restrict__ Vw2,
    const float* __restrict__ Vb2, float* __restrict__ sW,
    float* __restrict__ vout) {
  __shared__ float st_l[4][SD];
  __shared__ float red_l[4][4];
  const int b0 = blockIdx.x * 4;
  const int n = threadIdx.x;

#pragma unroll
  for (int i = 0; i < 4; ++i) st_l[i][n] = states[(b0 + i) * SD + n];
  __syncthreads();

  float aS[4], aV[4];
  const float b1n = b1[n], vb1n = Vb1[n];
#pragma unroll
  for (int i = 0; i < 4; ++i) { aS[i] = b1n; aV[i] = vb1n; }

#pragma unroll 4
  for (int k = 0; k < SD; ++k) {
    const float wv = W1[k * EMB + n];
    const float vw = Vw1[k * EMB + n];
#pragma unroll
    for (int i = 0; i < 4; ++i) {
      const float s = st_l[i][k];
      aS[i] = fmaf(s, wv, aS[i]);
      aV[i] = fmaf(s, vw, aV[i]);
    }
  }
#pragma unroll
  for (int i = 0; i < 4; ++i) sW[(b0 + i) * EMB + n] = aS[i];

  const float vw2 = Vw2[n];
#pragma unroll
  for (int i = 0; i < 4; ++i) {
    float c = fmaxf(aV[i], 0.f) * vw2;
#pragma unroll
    for (int off = 32; off; off >>= 1) c += __shfl_down(c, off);
    if ((n & 63) == 0) red_l[i][n >> 6] = c;
  }
  __syncthreads();
  if (n < 4)
    vout[b0 + n] = red_l[n][0] + red_l[n][1] + red_l[n][2] + red_l[n][3] + Vb2[0];
}

// ---------------------------------------------------------------------------
// Pack W1-bottom (128x256) and W2 (256x256) into bf16 B-fragment order.
// slot id = (t*16+u)*64 + L; elem j -> B[t*32+(L>>4)*8+j][u*16+(L&15)].
// ---------------------------------------------------------------------------
__global__ __launch_bounds__(256) void pack_kernel(
    const float* __restrict__ W1, const float* __restrict__ W2,
    __bf16* __restrict__ W1b_bf, __bf16* __restrict__ W2_bf) {
  const int ts = blockIdx.x * 256 + threadIdx.x;  // 0..12287
  if (ts < 4096) {                                // W1 bottom: t=0..3
    const int t = ts >> 10, rem = ts & 1023, u = rem >> 6, L = rem & 63;
    const int q = L >> 4, l15 = L & 15;
#pragma unroll
    for (int j = 0; j < 8; ++j) {
      const int k = t * 32 + q * 8 + j, nn = u * 16 + l15;
      W1b_bf[ts * 8 + j] = (__bf16)W1[(SD + k) * EMB + nn];
    }
  } else {                                        // W2: t=0..7
    const int ts2 = ts - 4096;
    const int t = ts2 >> 10, rem = ts2 & 1023, u = rem >> 6, L = rem & 63;
    const int q = L >> 4, l15 = L & 15;
#pragma unroll
    for (int j = 0; j < 8; ++j) {
      const int k = t * 32 + q * 8 + j, nn = u * 16 + l15;
      W2_bf[ts2 * 8 + j] = (__bf16)W2[k * EMB + nn];
    }
  }
}

// ---------------------------------------------------------------------------
// Main: 1024 blocks (one per b), 256 threads = 4 waves. Two passes of M=64.
// ---------------------------------------------------------------------------
__global__ __launch_bounds__(256) void main_kernel(
    const float* __restrict__ agent_qs, const float* __restrict__ b2g,
    const float* __restrict__ W3, const float* __restrict__ b3,
    const float* __restrict__ sW, const float* __restrict__ vv,
    const __bf16* __restrict__ W1b_bf, const __bf16* __restrict__ W2_bf,
    float* __restrict__ out) {
  __shared__ bf16x8 X_l[16 * 64];       // 16 KB: layer1 A-frags (M=64,K=128)
  __shared__ bf16x8 h1_l[32 * 64];      // 32 KB: layer2 A-frags (M=64,K=256)
  __shared__ __attribute__((aligned(16))) __bf16 qs_bf[A_N * NA_N];
  __shared__ float u_l[128];
  __shared__ int   inv_l[128];          // inv_l[s*8+a] = rank of agent a
  __shared__ int   pos_l[128];          // pos_l[s*8+r] = agent with rank r
  __shared__ float sW_l[EMB], b2_l[EMB], w3_l[EMB];
  __shared__ float adv_part[4][64];
  __shared__ float marg_l[128];         // marginal[s][prefix-row]

  const int b = blockIdx.x;
  const int n = threadIdx.x;
  const int w = n >> 6, L = n & 63, q = L >> 4, l15 = L & 15;

  if (n < 128) {
    qs_bf[n] = (__bf16)agent_qs[b * 128 + n];
    u_l[n] = jax_uniform((unsigned)(b * 128 + n));
  }
  sW_l[n] = sW[b * EMB + n];
  b2_l[n] = b2g[n];
  w3_l[n] = W3[n];
  __syncthreads();

  if (n < 128) {
    const int s = n >> 3, a = n & 7;
    const float u = u_l[n];
    int r = 0;
#pragma unroll
    for (int a2 = 0; a2 < A_N; ++a2) {
      const float u2 = u_l[s * 8 + a2];
      r += (u2 < u || (u2 == u && a2 < a)) ? 1 : 0;
    }
    inv_l[n] = r;
    pos_l[s * 8 + r] = a;
  }
  __syncthreads();

  for (int p = 0; p < 2; ++p) {
    // ---- build X in A-frag layout: X[m][k], m=s_loc*8+i, k=jcoal*16+na ----
#pragma unroll
    for (int g = 0; g < 4; ++g) {
      const int slot = g * 256 + n;
      const int gl = slot & 63, grp = slot >> 6;   // grp = t*4 + mt
      const int t = grp >> 2, mt = grp & 3;
      const int r15 = gl & 15, gq = gl >> 4;
      const int i = r15 & 7;                       // prefix length
      const int s_loc = mt * 2 + (r15 >> 3);
      const int jcoal = t * 2 + (gq >> 1);
      const int na0 = (gq & 1) * 8;
      bf16x8 val;
      if (jcoal <= i) {
        const int ag = inv_l[(p * 8 + s_loc) * 8 + jcoal];  // slot j <- qs[inv[j]]
        val = *(const bf16x8*)&qs_bf[ag * NA_N + na0];
      } else {
        val = zero8();
      }
      X_l[slot] = val;
    }
    __syncthreads();

    // ---- layer 1: (64x128) @ W1b (128x256), C init sW[col] ----
    f32x4 acc[4][4];
#pragma unroll
    for (int un = 0; un < 4; ++un) {
      const float sv = sW_l[(w * 4 + un) * 16 + l15];
#pragma unroll
      for (int mt = 0; mt < 4; ++mt) acc[mt][un] = splat4(sv);
    }
#pragma unroll
    for (int t = 0; t < 4; ++t) {
      bf16x8 af[4], bfr[4];
#pragma unroll
      for (int mt = 0; mt < 4; ++mt) af[mt] = X_l[(t * 4 + mt) * 64 + L];
#pragma unroll
      for (int un = 0; un < 4; ++un)
        bfr[un] = *(const bf16x8*)&W1b_bf[((t * 16 + w * 4 + un) * 64 + L) * 8];
#pragma unroll
      for (int mt = 0; mt < 4; ++mt)
#pragma unroll
        for (int un = 0; un < 4; ++un)
          acc[mt][un] = __builtin_amdgcn_mfma_f32_16x16x32_bf16(
              af[mt], bfr[un], acc[mt][un], 0, 0, 0);
    }

    // ---- epilogue: relu -> bf16 scatter into layer2 A-frag layout ----
    // value (row m, col c): lds elem ((c>>5)*4 + m>>4)*64 + ((c>>3)&3)*16 +
    //                       (m&15), sub-elem c&7.  Here m = mt*16+q*4+r,
    //                       c = (w*4+un)*16+l15.
    {
      __bf16* h1e = (__bf16*)h1_l;
#pragma unroll
      for (int un = 0; un < 4; ++un) {
        const int c = (w * 4 + un) * 16 + l15;
        const int t2 = c >> 5, q2 = (c >> 3) & 3, j2 = l15 & 7;
#pragma unroll
        for (int mt = 0; mt < 4; ++mt) {
#pragma unroll
          for (int r = 0; r < 4; ++r) {
            const float v = fmaxf(acc[mt][un][r], 0.f);
            h1e[(((t2 * 4 + mt) * 64) + q2 * 16 + q * 4 + r) * 8 + j2] =
                (__bf16)v;
          }
        }
      }
    }
    __syncthreads();

    // ---- layer 2: (64x256) @ W2 (256x256), C init b2[col] ----
#pragma unroll
    for (int un = 0; un < 4; ++un) {
      const float bv = b2_l[(w * 4 + un) * 16 + l15];
#pragma unroll
      for (int mt = 0; mt < 4; ++mt) acc[mt][un] = splat4(bv);
    }
#pragma unroll
    for (int t = 0; t < 8; ++t) {
      bf16x8 af[4], bfr[4];
#pragma unroll
      for (int mt = 0; mt < 4; ++mt) af[mt] = h1_l[(t * 4 + mt) * 64 + L];
#pragma unroll
      for (int un = 0; un < 4; ++un)
        bfr[un] = *(const bf16x8*)&W2_bf[((t * 16 + w * 4 + un) * 64 + L) * 8];
#pragma unroll
      for (int mt = 0; mt < 4; ++mt)
#pragma unroll
        for (int un = 0; un < 4; ++un)
          acc[mt][un] = __builtin_amdgcn_mfma_f32_16x16x32_bf16(
              af[mt], bfr[un], acc[mt][un], 0, 0, 0);
    }

    // ---- layer 3: relu * W3, reduce cols (16 lanes of each quad) ----
#pragma unroll
    for (int mt = 0; mt < 4; ++mt) {
#pragma unroll
      for (int r = 0; r < 4; ++r) {
        float sum = 0.f;
#pragma unroll
        for (int un = 0; un < 4; ++un)
          sum = fmaf(fmaxf(acc[mt][un][r], 0.f),
                     w3_l[(w * 4 + un) * 16 + l15], sum);
#pragma unroll
        for (int off = 1; off < 16; off <<= 1) sum += __shfl_xor(sum, off);
        if (l15 == 0) adv_part[w][mt * 16 + q * 4 + r] = sum;
      }
    }
    __syncthreads();
    if (n < 64)
      marg_l[p * 64 + n] = adv_part[0][n] + adv_part[1][n] +
                           adv_part[2][n] + adv_part[3][n];
    __syncthreads();
  }

  // ---- gather: agent a reads prefix-row pos_l[s*8+a] (validated mapping) --
  if (n < A_N) {
    float sh = 0.f;
#pragma unroll
    for (int s = 0; s < S_N; ++s) sh += marg_l[s * 8 + pos_l[s * 8 + n]];
    out[b * A_N + n] = sh * (1.f / 16.f) + b3[0] + vv[b];
  }
}

// ---------------------------------------------------------------------------
extern "C" void kernel_launch(void* const* d_in, const int* in_sizes, int n_in,
                              void* d_out, int out_size, void* d_ws,
                              size_t ws_size, hipStream_t stream) {
  const float* states   = (const float*)d_in[0];
  const float* agent_qs = (const float*)d_in[1];
  const float* W1       = (const float*)d_in[2];
  const float* b1       = (const float*)d_in[3];
  const float* W2       = (const float*)d_in[4];
  const float* b2       = (const float*)d_in[5];
  const float* W3       = (const float*)d_in[6];
  const float* b3       = (const float*)d_in[7];
  const float* Vw1      = (const float*)d_in[8];
  const float* Vb1      = (const float*)d_in[9];
  const float* Vw2      = (const float*)d_in[10];
  const float* Vb2      = (const float*)d_in[11];
  float* out = (float*)d_out;

  char* ws = (char*)d_ws;
  float*  sW     = (float*)(ws);                     // 1 MB
  float*  vv     = (float*)(ws + 1048576);           // 4 KB
  __bf16* W1b_bf = (__bf16*)(ws + 1052672);          // 64 KB
  __bf16* W2_bf  = (__bf16*)(ws + 1117184 + 1024);   // 128 KB @ 1118208

  prep_kernel<<<256, 256, 0, stream>>>(states, W1, b1, Vw1, Vb1, Vw2, Vb2,
                                       sW, vv);
  pack_kernel<<<48, 256, 0, stream>>>(W1, W2, W1b_bf, W2_bf);
  main_kernel<<<B_TOT, 256, 0, stream>>>(agent_qs, b2, W3, b3, sW, vv,
                                         W1b_bf, W2_bf, out);
}